// Round 7
// baseline (505.578 us; speedup 1.0000x reference)
//
#include <hip/hip_runtime.h>

#define B_SZ 16384
#define DIN  1024
#define HID  512
#define COMP 64

typedef __bf16 bf16_t;
typedef __bf16 bf16x4 __attribute__((ext_vector_type(4)));
typedef __bf16 bf16x8 __attribute__((ext_vector_type(8)));
typedef float  f32x4  __attribute__((ext_vector_type(4)));

#define MFMA16 __builtin_amdgcn_mfma_f32_16x16x32_bf16

__device__ __forceinline__ void gl2lds16(const void* g, void* l) {
    __builtin_amdgcn_global_load_lds(
        (const __attribute__((address_space(1))) void*)g,
        (__attribute__((address_space(3))) void*)l, 16, 0, 0);
}

__device__ __forceinline__ bf16x8 cvt8(float4 a, float4 b) {
    bf16x8 o;
    o[0] = (bf16_t)a.x; o[1] = (bf16_t)a.y;
    o[2] = (bf16_t)a.z; o[3] = (bf16_t)a.w;
    o[4] = (bf16_t)b.x; o[5] = (bf16_t)b.y;
    o[6] = (bf16_t)b.z; o[7] = (bf16_t)b.w;
    return o;
}

// ---------------------------------------------------------------------------
// prep (unchanged):
//   [0,1024)      : Wb transpose -> bf16 [512][1024]  (x2 branches)
//   [1024,1088)   : Wc transpose -> bf16 [64][512]    (x2 branches)
//   [1088,1104)   : prepG
//   [1104,3152)   : init f1/f2 with bias bc (atomic accumulation target)
// ---------------------------------------------------------------------------
__global__ __launch_bounds__(256) void k_prep(
    const float* __restrict__ Wb1, const float* __restrict__ Wb2,
    bf16_t* __restrict__ wbt1, bf16_t* __restrict__ wbt2,
    const float* __restrict__ Wc1, const float* __restrict__ Wc2,
    bf16_t* __restrict__ wct1, bf16_t* __restrict__ wct2,
    const float* __restrict__ Wf1, const float* __restrict__ bf1v,
    const float* __restrict__ Wf2, const float* __restrict__ bf2v,
    const float* __restrict__ bc1, const float* __restrict__ bc2,
    float* __restrict__ f1, float* __restrict__ f2,
    float* __restrict__ G, float* __restrict__ c)
{
    const int bid = blockIdx.x, tid = threadIdx.x;

    __shared__ float tile[32][33];
    const int tx = tid & 31, ty = tid >> 5;

    if (bid < 1024) {                     // Wb transpose: K=1024, N=512
        const int z = bid >> 9, t = bid & 511;
        const float* in  = z ? Wb2  : Wb1;
        bf16_t*      out = z ? wbt2 : wbt1;
        const int n0 = (t & 15) * 32, k0 = (t >> 4) * 32;
        #pragma unroll
        for (int i = 0; i < 4; i++)
            tile[ty + i * 8][tx] = in[(size_t)(k0 + ty + i * 8) * HID + n0 + tx];
        __syncthreads();
        #pragma unroll
        for (int i = 0; i < 4; i++)
            out[(size_t)(n0 + ty + i * 8) * DIN + k0 + tx] = (bf16_t)tile[tx][ty + i * 8];
    } else if (bid < 1088) {              // Wc transpose: K=512, N=64
        const int l = bid - 1024;
        const int z = l >> 5, t = l & 31;
        const float* in  = z ? Wc2  : Wc1;
        bf16_t*      out = z ? wct2 : wct1;
        const int n0 = (t & 1) * 32, k0 = (t >> 1) * 32;
        #pragma unroll
        for (int i = 0; i < 4; i++)
            tile[ty + i * 8][tx] = in[(size_t)(k0 + ty + i * 8) * COMP + n0 + tx];
        __syncthreads();
        #pragma unroll
        for (int i = 0; i < 4; i++)
            out[(size_t)(n0 + ty + i * 8) * HID + k0 + tx] = (bf16_t)tile[tx][ty + i * 8];
    } else if (bid < 1104) {              // prepG
        const int i = (bid - 1088) * 256 + tid;   // 0..4095
        float a0 = 0.f, a1 = 0.f;
        #pragma unroll 8
        for (int o = 0; o < 64; o++) {
            float w = Wf1[(size_t)i * 64 + o];
            a0 = fmaf(w, Wf2[o * 2 + 0], a0);
            a1 = fmaf(w, Wf2[o * 2 + 1], a1);
        }
        G[i]        = a0;
        G[4096 + i] = a1;
        if (i < 2) {
            float s = bf2v[i];
            for (int o = 0; o < 64; o++) s = fmaf(bf1v[o], Wf2[o * 2 + i], s);
            c[i] = s;
        }
    } else {                              // F init with bias
        const int l = bid - 1104;         // 0..2047
        const int z = l >> 10;
        const float* bc = z ? bc2 : bc1;
        float*       f  = z ? f2  : f1;
        const int i = (l & 1023) * 256 + tid;
        const int c4 = (i & 15) * 4;
        float4 v = make_float4(bc[c4], bc[c4 + 1], bc[c4 + 2], bc[c4 + 3]);
        reinterpret_cast<float4*>(f)[i] = v;
    }
}

// ---------------------------------------------------------------------------
// GEMM1 fused, fp32-X input, 128x128 tile, SINGLE-BUFFERED LDS, 4 BLOCKS/CU:
//   Round-6 lesson: 2 blocks x 4 waves = 8 waves/CU = same occupancy as one
//   8-wave block -> no overlap gain, double the sync cost. The m97/m103
//   reference (912 TF at this exact 128^2/BK64 shape) ran single-buffered
//   ~33 KB LDS at 3-4 blocks/CU (12-16 waves/CU): co-resident INDEPENDENT
//   blocks hide each other's barrier/drain windows (m114). So: drop the
//   double buffer, keep everything else from round 6.
//   LDS 33792 = max(A 16K + B 16K staging, Hs[128][132] epilogue alias)
//   -> 4 blocks/CU. Per tile: {cvt-write A(kt) from R (loaded one FULL
//   tile ago), gl2lds B(kt), R <- A(kt+1), vmcnt(8)+lgkmcnt(0), barrier,
//   frag reads + 32 MFMA, barrier}. vmcnt(8) drains the 4 B gl2lds
//   (issued before the 8 A-loads), keeps A in flight across the tile.
// ---------------------------------------------------------------------------
__global__ __launch_bounds__(256, 4) void k_gemm1f(
    const float* __restrict__ X1, const float* __restrict__ X2,
    const bf16_t* __restrict__ WT1, const bf16_t* __restrict__ WT2,
    const float* __restrict__ bias1, const float* __restrict__ bias2,
    const bf16_t* __restrict__ WC1, const bf16_t* __restrict__ WC2,
    float* __restrict__ F1, float* __restrict__ F2)
{
    const int bid = blockIdx.x;
    const int nid = (bid & 7) * 128 + (bid >> 3);  // bijective: 1024 = 8*128
    const int z   = nid >> 9;                      // branch (XCD 0-3 / 4-7)
    const int r9  = nid & 511;
    const int mb  = r9 >> 2;                       // 0..127 M tile
    const int nb  = r9 & 3;                        // 0..3   N tile (inner:
                                                   // 4 nb-siblings share an
                                                   // A panel on one XCD)
    const float*  X    = z ? X2    : X1;
    const bf16_t* WT   = z ? WT2   : WT1;
    const float*  bias = z ? bias2 : bias1;
    const bf16_t* WC   = z ? WC2   : WC1;
    float*        F    = z ? F2    : F1;

    const int m0 = mb * 128;
    const int n0 = nb * 128;

    // A staging at [0,16K), B staging at [16K,32K). Hs[128][132] aliases.
    __shared__ __align__(128) char smem[33792];

    const int tid  = threadIdx.x;
    const int lane = tid & 63;
    const int wave = tid >> 6;
    const int wm   = wave >> 1;      // 0..1
    const int wn   = wave & 1;       // 0..1
    const int l15  = lane & 15;
    const int g4   = lane >> 4;

    // ---- staging constants: sub-tile i covers rows i*32 + srow
    const int srow = tid >> 3;                    // 0..31
    const int sc   = (tid & 7) ^ (srow & 7);      // swizzled source k-chunk
    const float*  gX = X  + (size_t)(m0 + srow) * DIN + sc * 8;
    const bf16_t* gB = WT + (size_t)(n0 + srow) * DIN + sc * 8;
    const int ldst = tid * 16;                    // + i*4096 per sub-tile

    // ---- fragment-read constants (row&7 == l15&7)
    const int l7   = l15 & 7;
    const int lch0 = (g4 ^ l7) * 16;              // k-chunks 0-3 (u=0)
    const int lch1 = ((4 + g4) ^ l7) * 16;        // k-chunks 4-7 (u=1)
    const int abase = (wm * 64 + l15) * 128;      // A row byte base
    const int bbase = (wn * 64 + l15) * 128;      // B row byte base

    f32x4  acc[4][4] = {};
    float4 r[8];                                  // rolling A fp32 (32 VGPR)

    // ---- prologue: R <- A(0)
    #pragma unroll
    for (int i = 0; i < 4; i++) {
        r[2*i]   = *(const float4*)(gX + (size_t)i * 32 * DIN);
        r[2*i+1] = *(const float4*)(gX + (size_t)i * 32 * DIN + 4);
    }
    __builtin_amdgcn_sched_barrier(0);

    #pragma unroll 1
    for (int kt = 0; kt < 16; ++kt) {
        const int kc  = kt * 64;
        const int kc1 = (kt < 15 ? kt + 1 : 15) * 64;   // next A col (clamped)

        // ---- stage A(kt): cvt from R (loaded one full tile ago)
        #pragma unroll
        for (int i = 0; i < 4; i++)
            *(bf16x8*)(smem + i * 4096 + ldst) = cvt8(r[2*i], r[2*i+1]);
        __builtin_amdgcn_sched_barrier(0);
        // ---- stage B(kt) via gl2lds
        #pragma unroll
        for (int i = 0; i < 4; i++)
            gl2lds16(gB + (size_t)i * 32 * DIN + kc, smem + 16384 + i * 4096 + ldst);
        __builtin_amdgcn_sched_barrier(0);
        // ---- R <- A(kt+1)  (stays in flight across the whole tile)
        #pragma unroll
        for (int i = 0; i < 4; i++) {
            r[2*i]   = *(const float4*)(gX + (size_t)i * 32 * DIN + kc1);
            r[2*i+1] = *(const float4*)(gX + (size_t)i * 32 * DIN + kc1 + 4);
        }
        __builtin_amdgcn_sched_barrier(0);
        // drain B gl2lds (4 oldest) + cvt ds_writes; keep 8 A-loads flying
        asm volatile("s_waitcnt vmcnt(8) lgkmcnt(0)" ::: "memory");
        __builtin_amdgcn_s_barrier();
        __builtin_amdgcn_sched_barrier(0);

        // ---- frag reads + 32 MFMA
        bf16x8 a[4][2], b[4][2];
        #pragma unroll
        for (int mi = 0; mi < 4; mi++) {
            a[mi][0] = *(const bf16x8*)(smem + abase + mi * 2048 + lch0);
            a[mi][1] = *(const bf16x8*)(smem + abase + mi * 2048 + lch1);
        }
        #pragma unroll
        for (int ni = 0; ni < 4; ni++) {
            b[ni][0] = *(const bf16x8*)(smem + 16384 + bbase + ni * 2048 + lch0);
            b[ni][1] = *(const bf16x8*)(smem + 16384 + bbase + ni * 2048 + lch1);
        }
        __builtin_amdgcn_s_setprio(1);
        #pragma unroll
        for (int mi = 0; mi < 4; mi++)
            #pragma unroll
            for (int ni = 0; ni < 4; ni++) {
                acc[mi][ni] = MFMA16(a[mi][0], b[ni][0], acc[mi][ni], 0, 0, 0);
                acc[mi][ni] = MFMA16(a[mi][1], b[ni][1], acc[mi][ni], 0, 0, 0);
            }
        __builtin_amdgcn_s_setprio(0);
        __builtin_amdgcn_sched_barrier(0);
        // reads complete before each wave's MFMAs consumed them -> barrier
        // alone makes the buffer safe to overwrite next tile
        __builtin_amdgcn_s_barrier();
        __builtin_amdgcn_sched_barrier(0);
    }

    // drain stray tail A-loads before aliasing smem
    asm volatile("s_waitcnt vmcnt(0) lgkmcnt(0)" ::: "memory");
    __builtin_amdgcn_s_barrier();

    // ---- epilogue phase 1: Hs[128][132] = relu(H + bias)  (aliases smem)
    bf16_t* Hs = (bf16_t*)smem;
    float bv[4];
    #pragma unroll
    for (int ni = 0; ni < 4; ni++)
        bv[ni] = bias[n0 + wn * 64 + ni * 16 + l15];
    #pragma unroll
    for (int mi = 0; mi < 4; mi++) {
        const int lr = wm * 64 + mi * 16 + g4 * 4;
        #pragma unroll
        for (int ni = 0; ni < 4; ni++) {
            const int colL = wn * 64 + ni * 16 + l15;
            #pragma unroll
            for (int rr = 0; rr < 4; rr++) {
                float v = fmaxf(acc[mi][ni][rr] + bv[ni], 0.0f);
                Hs[(lr + rr) * 132 + colL] = (bf16_t)v;
            }
        }
    }
    __syncthreads();

    // ---- epilogue phase 2: each wave F[32 rows][64] += Hs-slice @ wct
    f32x4 acc2[2][4] = {};
    #pragma unroll
    for (int kk = 0; kk < 128; kk += 32) {
        bf16x8 af2[2];
        #pragma unroll
        for (int m2 = 0; m2 < 2; m2++)
            af2[m2] = *(const bf16x8*)(Hs + (wave * 32 + m2 * 16 + l15) * 132 + kk + g4 * 8);
        #pragma unroll
        for (int ni = 0; ni < 4; ni++) {
            bf16x8 bw = *(const bf16x8*)(&WC[(size_t)(ni * 16 + l15) * HID + n0 + kk + g4 * 8]);
            #pragma unroll
            for (int m2 = 0; m2 < 2; m2++)
                acc2[m2][ni] = MFMA16(af2[m2], bw, acc2[m2][ni], 0, 0, 0);
        }
    }
    #pragma unroll
    for (int m2 = 0; m2 < 2; m2++) {
        const int rbase = m0 + wave * 32 + m2 * 16 + g4 * 4;
        #pragma unroll
        for (int ni = 0; ni < 4; ni++) {
            const int col = ni * 16 + l15;
            #pragma unroll
            for (int rr = 0; rr < 4; rr++)
                unsafeAtomicAdd(&F[(size_t)(rbase + rr) * COMP + col], acc2[m2][ni][rr]);
        }
    }
}

// ---------------------------------------------------------------------------
// bilinear (fp32, G-broadcast form — unchanged):
//   out[b][j] = f2[b,:] . G_j . f1[b,:]^T + c[j]
// ---------------------------------------------------------------------------
__global__ __launch_bounds__(256) void k_bilinear(
    const float* __restrict__ f1, const float* __restrict__ f2,
    const float* __restrict__ G, const float* __restrict__ c,
    float* __restrict__ out)
{
    __shared__ float Gs[2][4096];
    __shared__ float f1t[64][66];
    __shared__ float f2t[64][66];
    __shared__ float part[4][64];

    const int tid = threadIdx.x;
    const int s0  = blockIdx.x * 64;

    for (int i = tid; i < 2048; i += 256)
        reinterpret_cast<float4*>(&Gs[0][0])[i] =
            reinterpret_cast<const float4*>(G)[i];

    #pragma unroll
    for (int rr = 0; rr < 4; rr++) {
        const int row = (tid >> 4) + rr * 16;     // sample within tile
        const int c4  = (tid & 15) * 4;
        float4 v1 = *reinterpret_cast<const float4*>(&f1[(size_t)(s0 + row) * 64 + c4]);
        float4 v2 = *reinterpret_cast<const float4*>(&f2[(size_t)(s0 + row) * 64 + c4]);
        f1t[c4 + 0][row] = v1.x; f1t[c4 + 1][row] = v1.y;
        f1t[c4 + 2][row] = v1.z; f1t[c4 + 3][row] = v1.w;
        f2t[c4 + 0][row] = v2.x; f2t[c4 + 1][row] = v2.y;
        f2t[c4 + 2][row] = v2.z; f2t[c4 + 3][row] = v2.w;
    }
    __syncthreads();

    const int lane = tid & 63;        // sample
    const int wv   = tid >> 6;        // 0..3
    const int j    = wv & 1;
    const int qh   = (wv >> 1) * 32;

    float tq[32];
    #pragma unroll
    for (int q = 0; q < 32; q++) tq[q] = 0.f;

    #pragma unroll 4
    for (int p = 0; p < 64; p++) {
        const float f2p = f2t[p][lane];
        const float* Gp = &Gs[j][p * 64 + qh];
        #pragma unroll
        for (int q4 = 0; q4 < 8; q4++) {
            float4 g = *reinterpret_cast<const float4*>(Gp + q4 * 4);
            tq[q4 * 4 + 0] = fmaf(f2p, g.x, tq[q4 * 4 + 0]);
            tq[q4 * 4 + 1] = fmaf(f2p, g.y, tq[q4 * 4 + 1]);
            tq[q4 * 4 + 2] = fmaf(f2p, g.z, tq[q4 * 4 + 2]);
            tq[q4 * 4 + 3] = fmaf(f2p, g.w, tq[q4 * 4 + 3]);
        }
    }

    float o = 0.f;
    #pragma unroll
    for (int q = 0; q < 32; q++)
        o = fmaf(f1t[qh + q][lane], tq[q], o);

    part[wv][lane] = o;
    __syncthreads();

    if (wv < 2) {
        float r = part[wv][lane] + part[wv + 2][lane] + c[wv];
        out[(size_t)(s0 + lane) * 2 + wv] = r;
    }
}

// ---------------------------------------------------------------------------
extern "C" void kernel_launch(void* const* d_in, const int* in_sizes, int n_in,
                              void* d_out, int out_size, void* d_ws, size_t ws_size,
                              hipStream_t stream)
{
    const float* x1  = (const float*)d_in[0];
    const float* x2  = (const float*)d_in[1];
    const float* Wb1 = (const float*)d_in[2];
    const float* bb1 = (const float*)d_in[3];
    const float* Wb2 = (const float*)d_in[4];
    const float* bb2 = (const float*)d_in[5];
    const float* Wc1 = (const float*)d_in[6];
    const float* bc1 = (const float*)d_in[7];
    const float* Wc2 = (const float*)d_in[8];
    const float* bc2 = (const float*)d_in[9];
    const float* Wf1 = (const float*)d_in[10];
    const float* bf1v = (const float*)d_in[11];
    const float* Wf2 = (const float*)d_in[12];
    const float* bf2v = (const float*)d_in[13];
    float* out = (float*)d_out;

    // workspace carve-up (~10.8 MB)
    char* ws = (char*)d_ws;
    bf16_t* wbt1 = (bf16_t*)ws; ws += (size_t)HID * DIN * 2;
    bf16_t* wbt2 = (bf16_t*)ws; ws += (size_t)HID * DIN * 2;
    bf16_t* wct1 = (bf16_t*)ws; ws += (size_t)COMP * HID * 2;
    bf16_t* wct2 = (bf16_t*)ws; ws += (size_t)COMP * HID * 2;
    float*  f1   = (float*)ws;  ws += (size_t)B_SZ * COMP * 4;
    float*  f2   = (float*)ws;  ws += (size_t)B_SZ * COMP * 4;
    float*  G    = (float*)ws;  ws += (size_t)2 * 4096 * 4;
    float*  c    = (float*)ws;  ws += 256;

    k_prep<<<3152, 256, 0, stream>>>(Wb1, Wb2, wbt1, wbt2,
                                     Wc1, Wc2, wct1, wct2,
                                     Wf1, bf1v, Wf2, bf2v,
                                     bc1, bc2, f1, f2, G, c);
    k_gemm1f<<<1024, 256, 0, stream>>>(x1, x2, wbt1, wbt2, bb1, bb2,
                                       wct1, wct2, f1, f2);
    k_bilinear<<<256, 256, 0, stream>>>(f1, f2, G, c, out);
}

// Round 8
// 242.972 us; speedup vs baseline: 2.0808x; 2.0808x over previous
//
#include <hip/hip_runtime.h>

#define B_SZ 16384
#define DIN  1024
#define HID  512
#define COMP 64

typedef __bf16 bf16_t;
typedef __bf16 bf16x4 __attribute__((ext_vector_type(4)));
typedef __bf16 bf16x8 __attribute__((ext_vector_type(8)));
typedef float  f32x4  __attribute__((ext_vector_type(4)));

#define MFMA16 __builtin_amdgcn_mfma_f32_16x16x32_bf16

__device__ __forceinline__ void gl2lds16(const void* g, void* l) {
    __builtin_amdgcn_global_load_lds(
        (const __attribute__((address_space(1))) void*)g,
        (__attribute__((address_space(3))) void*)l, 16, 0, 0);
}

__device__ __forceinline__ bf16x8 cvt8(float4 a, float4 b) {
    bf16x8 o;
    o[0] = (bf16_t)a.x; o[1] = (bf16_t)a.y;
    o[2] = (bf16_t)a.z; o[3] = (bf16_t)a.w;
    o[4] = (bf16_t)b.x; o[5] = (bf16_t)b.y;
    o[6] = (bf16_t)b.z; o[7] = (bf16_t)b.w;
    return o;
}

// ---------------------------------------------------------------------------
// prep (unchanged):
//   [0,1024)      : Wb transpose -> bf16 [512][1024]  (x2 branches)
//   [1024,1088)   : Wc transpose -> bf16 [64][512]    (x2 branches)
//   [1088,1104)   : prepG
//   [1104,3152)   : init f1/f2 with bias bc (atomic accumulation target)
// ---------------------------------------------------------------------------
__global__ __launch_bounds__(256) void k_prep(
    const float* __restrict__ Wb1, const float* __restrict__ Wb2,
    bf16_t* __restrict__ wbt1, bf16_t* __restrict__ wbt2,
    const float* __restrict__ Wc1, const float* __restrict__ Wc2,
    bf16_t* __restrict__ wct1, bf16_t* __restrict__ wct2,
    const float* __restrict__ Wf1, const float* __restrict__ bf1v,
    const float* __restrict__ Wf2, const float* __restrict__ bf2v,
    const float* __restrict__ bc1, const float* __restrict__ bc2,
    float* __restrict__ f1, float* __restrict__ f2,
    float* __restrict__ G, float* __restrict__ c)
{
    const int bid = blockIdx.x, tid = threadIdx.x;

    __shared__ float tile[32][33];
    const int tx = tid & 31, ty = tid >> 5;

    if (bid < 1024) {                     // Wb transpose: K=1024, N=512
        const int z = bid >> 9, t = bid & 511;
        const float* in  = z ? Wb2  : Wb1;
        bf16_t*      out = z ? wbt2 : wbt1;
        const int n0 = (t & 15) * 32, k0 = (t >> 4) * 32;
        #pragma unroll
        for (int i = 0; i < 4; i++)
            tile[ty + i * 8][tx] = in[(size_t)(k0 + ty + i * 8) * HID + n0 + tx];
        __syncthreads();
        #pragma unroll
        for (int i = 0; i < 4; i++)
            out[(size_t)(n0 + ty + i * 8) * DIN + k0 + tx] = (bf16_t)tile[tx][ty + i * 8];
    } else if (bid < 1088) {              // Wc transpose: K=512, N=64
        const int l = bid - 1024;
        const int z = l >> 5, t = l & 31;
        const float* in  = z ? Wc2  : Wc1;
        bf16_t*      out = z ? wct2 : wct1;
        const int n0 = (t & 1) * 32, k0 = (t >> 1) * 32;
        #pragma unroll
        for (int i = 0; i < 4; i++)
            tile[ty + i * 8][tx] = in[(size_t)(k0 + ty + i * 8) * COMP + n0 + tx];
        __syncthreads();
        #pragma unroll
        for (int i = 0; i < 4; i++)
            out[(size_t)(n0 + ty + i * 8) * HID + k0 + tx] = (bf16_t)tile[tx][ty + i * 8];
    } else if (bid < 1104) {              // prepG
        const int i = (bid - 1088) * 256 + tid;   // 0..4095
        float a0 = 0.f, a1 = 0.f;
        #pragma unroll 8
        for (int o = 0; o < 64; o++) {
            float w = Wf1[(size_t)i * 64 + o];
            a0 = fmaf(w, Wf2[o * 2 + 0], a0);
            a1 = fmaf(w, Wf2[o * 2 + 1], a1);
        }
        G[i]        = a0;
        G[4096 + i] = a1;
        if (i < 2) {
            float s = bf2v[i];
            for (int o = 0; o < 64; o++) s = fmaf(bf1v[o], Wf2[o * 2 + i], s);
            c[i] = s;
        }
    } else {                              // F init with bias
        const int l = bid - 1104;         // 0..2047
        const int z = l >> 10;
        const float* bc = z ? bc2 : bc1;
        float*       f  = z ? f2  : f1;
        const int i = (l & 1023) * 256 + tid;
        const int c4 = (i & 15) * 4;
        float4 v = make_float4(bc[c4], bc[c4 + 1], bc[c4 + 2], bc[c4 + 3]);
        reinterpret_cast<float4*>(f)[i] = v;
    }
}

// ---------------------------------------------------------------------------
// GEMM1 fused, fp32-X input, 128x128 tile, single-buffered LDS, 3 BLOCKS/CU:
//   Round-7 post-mortem: __launch_bounds__(256,4) capped VGPR at 128 < the
//   ~175-reg live set -> acc spilled to scratch (WRITE_SIZE 706 MB, VGPR=64,
//   3.7x slower). The occupancy mechanism itself was CONFIRMED (44% vs 20%).
//   Fix: (256,3) -> VGPR cap ~170, no spill, 3 blocks/CU = 12 waves/CU
//   (m97's proven operating point: 164 VGPR, ~3 blocks/CU, 912 TF).
//   Everything else identical to round 7.
// ---------------------------------------------------------------------------
__global__ __launch_bounds__(256, 3) void k_gemm1f(
    const float* __restrict__ X1, const float* __restrict__ X2,
    const bf16_t* __restrict__ WT1, const bf16_t* __restrict__ WT2,
    const float* __restrict__ bias1, const float* __restrict__ bias2,
    const bf16_t* __restrict__ WC1, const bf16_t* __restrict__ WC2,
    float* __restrict__ F1, float* __restrict__ F2)
{
    const int bid = blockIdx.x;
    const int nid = (bid & 7) * 128 + (bid >> 3);  // bijective: 1024 = 8*128
    const int z   = nid >> 9;                      // branch (XCD 0-3 / 4-7)
    const int r9  = nid & 511;
    const int mb  = r9 >> 2;                       // 0..127 M tile
    const int nb  = r9 & 3;                        // 0..3   N tile (inner:
                                                   // 4 nb-siblings share an
                                                   // A panel on one XCD)
    const float*  X    = z ? X2    : X1;
    const bf16_t* WT   = z ? WT2   : WT1;
    const float*  bias = z ? bias2 : bias1;
    const bf16_t* WC   = z ? WC2   : WC1;
    float*        F    = z ? F2    : F1;

    const int m0 = mb * 128;
    const int n0 = nb * 128;

    // A staging at [0,16K), B staging at [16K,32K). Hs[128][132] aliases.
    __shared__ __align__(128) char smem[33792];

    const int tid  = threadIdx.x;
    const int lane = tid & 63;
    const int wave = tid >> 6;
    const int wm   = wave >> 1;      // 0..1
    const int wn   = wave & 1;       // 0..1
    const int l15  = lane & 15;
    const int g4   = lane >> 4;

    // ---- staging constants: sub-tile i covers rows i*32 + srow
    const int srow = tid >> 3;                    // 0..31
    const int sc   = (tid & 7) ^ (srow & 7);      // swizzled source k-chunk
    const float*  gX = X  + (size_t)(m0 + srow) * DIN + sc * 8;
    const bf16_t* gB = WT + (size_t)(n0 + srow) * DIN + sc * 8;
    const int ldst = tid * 16;                    // + i*4096 per sub-tile

    // ---- fragment-read constants (row&7 == l15&7)
    const int l7   = l15 & 7;
    const int lch0 = (g4 ^ l7) * 16;              // k-chunks 0-3 (u=0)
    const int lch1 = ((4 + g4) ^ l7) * 16;        // k-chunks 4-7 (u=1)
    const int abase = (wm * 64 + l15) * 128;      // A row byte base
    const int bbase = (wn * 64 + l15) * 128;      // B row byte base

    f32x4  acc[4][4] = {};
    float4 r[8];                                  // rolling A fp32 (32 VGPR)

    // ---- prologue: R <- A(0)
    #pragma unroll
    for (int i = 0; i < 4; i++) {
        r[2*i]   = *(const float4*)(gX + (size_t)i * 32 * DIN);
        r[2*i+1] = *(const float4*)(gX + (size_t)i * 32 * DIN + 4);
    }
    __builtin_amdgcn_sched_barrier(0);

    #pragma unroll 1
    for (int kt = 0; kt < 16; ++kt) {
        const int kc  = kt * 64;
        const int kc1 = (kt < 15 ? kt + 1 : 15) * 64;   // next A col (clamped)

        // ---- stage A(kt): cvt from R (loaded one full tile ago)
        #pragma unroll
        for (int i = 0; i < 4; i++)
            *(bf16x8*)(smem + i * 4096 + ldst) = cvt8(r[2*i], r[2*i+1]);
        __builtin_amdgcn_sched_barrier(0);
        // ---- stage B(kt) via gl2lds
        #pragma unroll
        for (int i = 0; i < 4; i++)
            gl2lds16(gB + (size_t)i * 32 * DIN + kc, smem + 16384 + i * 4096 + ldst);
        __builtin_amdgcn_sched_barrier(0);
        // ---- R <- A(kt+1)  (stays in flight across the whole tile)
        #pragma unroll
        for (int i = 0; i < 4; i++) {
            r[2*i]   = *(const float4*)(gX + (size_t)i * 32 * DIN + kc1);
            r[2*i+1] = *(const float4*)(gX + (size_t)i * 32 * DIN + kc1 + 4);
        }
        __builtin_amdgcn_sched_barrier(0);
        // drain B gl2lds (4 oldest) + cvt ds_writes; keep 8 A-loads flying
        asm volatile("s_waitcnt vmcnt(8) lgkmcnt(0)" ::: "memory");
        __builtin_amdgcn_s_barrier();
        __builtin_amdgcn_sched_barrier(0);

        // ---- frag reads + 32 MFMA
        bf16x8 a[4][2], b[4][2];
        #pragma unroll
        for (int mi = 0; mi < 4; mi++) {
            a[mi][0] = *(const bf16x8*)(smem + abase + mi * 2048 + lch0);
            a[mi][1] = *(const bf16x8*)(smem + abase + mi * 2048 + lch1);
        }
        #pragma unroll
        for (int ni = 0; ni < 4; ni++) {
            b[ni][0] = *(const bf16x8*)(smem + 16384 + bbase + ni * 2048 + lch0);
            b[ni][1] = *(const bf16x8*)(smem + 16384 + bbase + ni * 2048 + lch1);
        }
        __builtin_amdgcn_s_setprio(1);
        #pragma unroll
        for (int mi = 0; mi < 4; mi++)
            #pragma unroll
            for (int ni = 0; ni < 4; ni++) {
                acc[mi][ni] = MFMA16(a[mi][0], b[ni][0], acc[mi][ni], 0, 0, 0);
                acc[mi][ni] = MFMA16(a[mi][1], b[ni][1], acc[mi][ni], 0, 0, 0);
            }
        __builtin_amdgcn_s_setprio(0);
        __builtin_amdgcn_sched_barrier(0);
        // reads complete before each wave's MFMAs consumed them -> barrier
        // alone makes the buffer safe to overwrite next tile
        __builtin_amdgcn_s_barrier();
        __builtin_amdgcn_sched_barrier(0);
    }

    // drain stray tail A-loads before aliasing smem
    asm volatile("s_waitcnt vmcnt(0) lgkmcnt(0)" ::: "memory");
    __builtin_amdgcn_s_barrier();

    // ---- epilogue phase 1: Hs[128][132] = relu(H + bias)  (aliases smem)
    bf16_t* Hs = (bf16_t*)smem;
    float bv[4];
    #pragma unroll
    for (int ni = 0; ni < 4; ni++)
        bv[ni] = bias[n0 + wn * 64 + ni * 16 + l15];
    #pragma unroll
    for (int mi = 0; mi < 4; mi++) {
        const int lr = wm * 64 + mi * 16 + g4 * 4;
        #pragma unroll
        for (int ni = 0; ni < 4; ni++) {
            const int colL = wn * 64 + ni * 16 + l15;
            #pragma unroll
            for (int rr = 0; rr < 4; rr++) {
                float v = fmaxf(acc[mi][ni][rr] + bv[ni], 0.0f);
                Hs[(lr + rr) * 132 + colL] = (bf16_t)v;
            }
        }
    }
    __syncthreads();

    // ---- epilogue phase 2: each wave F[32 rows][64] += Hs-slice @ wct
    f32x4 acc2[2][4] = {};
    #pragma unroll
    for (int kk = 0; kk < 128; kk += 32) {
        bf16x8 af2[2];
        #pragma unroll
        for (int m2 = 0; m2 < 2; m2++)
            af2[m2] = *(const bf16x8*)(Hs + (wave * 32 + m2 * 16 + l15) * 132 + kk + g4 * 8);
        #pragma unroll
        for (int ni = 0; ni < 4; ni++) {
            bf16x8 bw = *(const bf16x8*)(&WC[(size_t)(ni * 16 + l15) * HID + n0 + kk + g4 * 8]);
            #pragma unroll
            for (int m2 = 0; m2 < 2; m2++)
                acc2[m2][ni] = MFMA16(af2[m2], bw, acc2[m2][ni], 0, 0, 0);
        }
    }
    #pragma unroll
    for (int m2 = 0; m2 < 2; m2++) {
        const int rbase = m0 + wave * 32 + m2 * 16 + g4 * 4;
        #pragma unroll
        for (int ni = 0; ni < 4; ni++) {
            const int col = ni * 16 + l15;
            #pragma unroll
            for (int rr = 0; rr < 4; rr++)
                unsafeAtomicAdd(&F[(size_t)(rbase + rr) * COMP + col], acc2[m2][ni][rr]);
        }
    }
}

// ---------------------------------------------------------------------------
// bilinear (fp32, G-broadcast form — unchanged):
//   out[b][j] = f2[b,:] . G_j . f1[b,:]^T + c[j]
// ---------------------------------------------------------------------------
__global__ __launch_bounds__(256) void k_bilinear(
    const float* __restrict__ f1, const float* __restrict__ f2,
    const float* __restrict__ G, const float* __restrict__ c,
    float* __restrict__ out)
{
    __shared__ float Gs[2][4096];
    __shared__ float f1t[64][66];
    __shared__ float f2t[64][66];
    __shared__ float part[4][64];

    const int tid = threadIdx.x;
    const int s0  = blockIdx.x * 64;

    for (int i = tid; i < 2048; i += 256)
        reinterpret_cast<float4*>(&Gs[0][0])[i] =
            reinterpret_cast<const float4*>(G)[i];

    #pragma unroll
    for (int rr = 0; rr < 4; rr++) {
        const int row = (tid >> 4) + rr * 16;     // sample within tile
        const int c4  = (tid & 15) * 4;
        float4 v1 = *reinterpret_cast<const float4*>(&f1[(size_t)(s0 + row) * 64 + c4]);
        float4 v2 = *reinterpret_cast<const float4*>(&f2[(size_t)(s0 + row) * 64 + c4]);
        f1t[c4 + 0][row] = v1.x; f1t[c4 + 1][row] = v1.y;
        f1t[c4 + 2][row] = v1.z; f1t[c4 + 3][row] = v1.w;
        f2t[c4 + 0][row] = v2.x; f2t[c4 + 1][row] = v2.y;
        f2t[c4 + 2][row] = v2.z; f2t[c4 + 3][row] = v2.w;
    }
    __syncthreads();

    const int lane = tid & 63;        // sample
    const int wv   = tid >> 6;        // 0..3
    const int j    = wv & 1;
    const int qh   = (wv >> 1) * 32;

    float tq[32];
    #pragma unroll
    for (int q = 0; q < 32; q++) tq[q] = 0.f;

    #pragma unroll 4
    for (int p = 0; p < 64; p++) {
        const float f2p = f2t[p][lane];
        const float* Gp = &Gs[j][p * 64 + qh];
        #pragma unroll
        for (int q4 = 0; q4 < 8; q4++) {
            float4 g = *reinterpret_cast<const float4*>(Gp + q4 * 4);
            tq[q4 * 4 + 0] = fmaf(f2p, g.x, tq[q4 * 4 + 0]);
            tq[q4 * 4 + 1] = fmaf(f2p, g.y, tq[q4 * 4 + 1]);
            tq[q4 * 4 + 2] = fmaf(f2p, g.z, tq[q4 * 4 + 2]);
            tq[q4 * 4 + 3] = fmaf(f2p, g.w, tq[q4 * 4 + 3]);
        }
    }

    float o = 0.f;
    #pragma unroll
    for (int q = 0; q < 32; q++)
        o = fmaf(f1t[qh + q][lane], tq[q], o);

    part[wv][lane] = o;
    __syncthreads();

    if (wv < 2) {
        float r = part[wv][lane] + part[wv + 2][lane] + c[wv];
        out[(size_t)(s0 + lane) * 2 + wv] = r;
    }
}

// ---------------------------------------------------------------------------
extern "C" void kernel_launch(void* const* d_in, const int* in_sizes, int n_in,
                              void* d_out, int out_size, void* d_ws, size_t ws_size,
                              hipStream_t stream)
{
    const float* x1  = (const float*)d_in[0];
    const float* x2  = (const float*)d_in[1];
    const float* Wb1 = (const float*)d_in[2];
    const float* bb1 = (const float*)d_in[3];
    const float* Wb2 = (const float*)d_in[4];
    const float* bb2 = (const float*)d_in[5];
    const float* Wc1 = (const float*)d_in[6];
    const float* bc1 = (const float*)d_in[7];
    const float* Wc2 = (const float*)d_in[8];
    const float* bc2 = (const float*)d_in[9];
    const float* Wf1 = (const float*)d_in[10];
    const float* bf1v = (const float*)d_in[11];
    const float* Wf2 = (const float*)d_in[12];
    const float* bf2v = (const float*)d_in[13];
    float* out = (float*)d_out;

    // workspace carve-up (~10.8 MB)
    char* ws = (char*)d_ws;
    bf16_t* wbt1 = (bf16_t*)ws; ws += (size_t)HID * DIN * 2;
    bf16_t* wbt2 = (bf16_t*)ws; ws += (size_t)HID * DIN * 2;
    bf16_t* wct1 = (bf16_t*)ws; ws += (size_t)COMP * HID * 2;
    bf16_t* wct2 = (bf16_t*)ws; ws += (size_t)COMP * HID * 2;
    float*  f1   = (float*)ws;  ws += (size_t)B_SZ * COMP * 4;
    float*  f2   = (float*)ws;  ws += (size_t)B_SZ * COMP * 4;
    float*  G    = (float*)ws;  ws += (size_t)2 * 4096 * 4;
    float*  c    = (float*)ws;  ws += 256;

    k_prep<<<3152, 256, 0, stream>>>(Wb1, Wb2, wbt1, wbt2,
                                     Wc1, Wc2, wct1, wct2,
                                     Wf1, bf1v, Wf2, bf2v,
                                     bc1, bc2, f1, f2, G, c);
    k_gemm1f<<<1024, 256, 0, stream>>>(x1, x2, wbt1, wbt2, bb1, bb2,
                                       wct1, wct2, f1, f2);
    k_bilinear<<<256, 256, 0, stream>>>(f1, f2, G, c, out);
}

// Round 9
// 214.694 us; speedup vs baseline: 2.3549x; 1.1317x over previous
//
#include <hip/hip_runtime.h>

#define B_SZ 16384
#define DIN  1024
#define HID  512
#define COMP 64

typedef __bf16 bf16_t;
typedef __bf16 bf16x4 __attribute__((ext_vector_type(4)));
typedef __bf16 bf16x8 __attribute__((ext_vector_type(8)));
typedef float  f32x4  __attribute__((ext_vector_type(4)));

#define MFMA16 __builtin_amdgcn_mfma_f32_16x16x32_bf16

__device__ __forceinline__ void gl2lds16(const void* g, void* l) {
    __builtin_amdgcn_global_load_lds(
        (const __attribute__((address_space(1))) void*)g,
        (__attribute__((address_space(3))) void*)l, 16, 0, 0);
}

__device__ __forceinline__ bf16x8 cvt8(float4 a, float4 b) {
    bf16x8 o;
    o[0] = (bf16_t)a.x; o[1] = (bf16_t)a.y;
    o[2] = (bf16_t)a.z; o[3] = (bf16_t)a.w;
    o[4] = (bf16_t)b.x; o[5] = (bf16_t)b.y;
    o[6] = (bf16_t)b.z; o[7] = (bf16_t)b.w;
    return o;
}

// ---------------------------------------------------------------------------
// prep (unchanged from round 5):
//   [0,1024)      : Wb transpose -> bf16 [512][1024]  (x2 branches)
//   [1024,1088)   : Wc transpose -> bf16 [64][512]    (x2 branches)
//   [1088,1104)   : prepG
//   [1104,3152)   : init f1/f2 with bias bc (atomic accumulation target)
// ---------------------------------------------------------------------------
__global__ __launch_bounds__(256) void k_prep(
    const float* __restrict__ Wb1, const float* __restrict__ Wb2,
    bf16_t* __restrict__ wbt1, bf16_t* __restrict__ wbt2,
    const float* __restrict__ Wc1, const float* __restrict__ Wc2,
    bf16_t* __restrict__ wct1, bf16_t* __restrict__ wct2,
    const float* __restrict__ Wf1, const float* __restrict__ bf1v,
    const float* __restrict__ Wf2, const float* __restrict__ bf2v,
    const float* __restrict__ bc1, const float* __restrict__ bc2,
    float* __restrict__ f1, float* __restrict__ f2,
    float* __restrict__ G, float* __restrict__ c)
{
    const int bid = blockIdx.x, tid = threadIdx.x;

    __shared__ float tile[32][33];
    const int tx = tid & 31, ty = tid >> 5;

    if (bid < 1024) {                     // Wb transpose: K=1024, N=512
        const int z = bid >> 9, t = bid & 511;
        const float* in  = z ? Wb2  : Wb1;
        bf16_t*      out = z ? wbt2 : wbt1;
        const int n0 = (t & 15) * 32, k0 = (t >> 4) * 32;
        #pragma unroll
        for (int i = 0; i < 4; i++)
            tile[ty + i * 8][tx] = in[(size_t)(k0 + ty + i * 8) * HID + n0 + tx];
        __syncthreads();
        #pragma unroll
        for (int i = 0; i < 4; i++)
            out[(size_t)(n0 + ty + i * 8) * DIN + k0 + tx] = (bf16_t)tile[tx][ty + i * 8];
    } else if (bid < 1088) {              // Wc transpose: K=512, N=64
        const int l = bid - 1024;
        const int z = l >> 5, t = l & 31;
        const float* in  = z ? Wc2  : Wc1;
        bf16_t*      out = z ? wct2 : wct1;
        const int n0 = (t & 1) * 32, k0 = (t >> 1) * 32;
        #pragma unroll
        for (int i = 0; i < 4; i++)
            tile[ty + i * 8][tx] = in[(size_t)(k0 + ty + i * 8) * COMP + n0 + tx];
        __syncthreads();
        #pragma unroll
        for (int i = 0; i < 4; i++)
            out[(size_t)(n0 + ty + i * 8) * HID + k0 + tx] = (bf16_t)tile[tx][ty + i * 8];
    } else if (bid < 1104) {              // prepG
        const int i = (bid - 1088) * 256 + tid;   // 0..4095
        float a0 = 0.f, a1 = 0.f;
        #pragma unroll 8
        for (int o = 0; o < 64; o++) {
            float w = Wf1[(size_t)i * 64 + o];
            a0 = fmaf(w, Wf2[o * 2 + 0], a0);
            a1 = fmaf(w, Wf2[o * 2 + 1], a1);
        }
        G[i]        = a0;
        G[4096 + i] = a1;
        if (i < 2) {
            float s = bf2v[i];
            for (int o = 0; o < 64; o++) s = fmaf(bf1v[o], Wf2[o * 2 + i], s);
            c[i] = s;
        }
    } else {                              // F init with bias
        const int l = bid - 1104;         // 0..2047
        const int z = l >> 10;
        const float* bc = z ? bc2 : bc1;
        float*       f  = z ? f2  : f1;
        const int i = (l & 1023) * 256 + tid;
        const int c4 = (i & 15) * 4;
        float4 v = make_float4(bc[c4], bc[c4 + 1], bc[c4 + 2], bc[c4 + 3]);
        reinterpret_cast<float4*>(f)[i] = v;
    }
}

// ---------------------------------------------------------------------------
// GEMM1 fused, fp32-X input, 256x256 tile, single-barrier tile (round-5
// base, measured 76-79 us) + 2-DEEP SPREAD A-PREFETCH:
//   rB <- A(kt+1)h1 and B(kt+1) gl2lds issue at TILE TOP (full-tile cover);
//   rA <- A(kt+2)h0 issues mid-tile. Every load->consume distance >= one
//   compute phase; issue bursts spread over 3 points -> ~2x average
//   outstanding bytes (Little's-law fix for the 1.9 TB/s latency-bound
//   A-stream). vmcnt FIFO: end-of-tile vmcnt(4) drains B, keeps rA;
//   compiler auto-inserts vmcnt(8) before each cvt consumption.
// ---------------------------------------------------------------------------
__global__ __launch_bounds__(512, 2) void k_gemm1f(
    const float* __restrict__ X1, const float* __restrict__ X2,
    const bf16_t* __restrict__ WT1, const bf16_t* __restrict__ WT2,
    const float* __restrict__ bias1, const float* __restrict__ bias2,
    const bf16_t* __restrict__ WC1, const bf16_t* __restrict__ WC2,
    float* __restrict__ F1, float* __restrict__ F2)
{
    const int bid = blockIdx.x;
    const int nid = (bid & 7) * 32 + (bid >> 3);   // bijective: 256 = 8*32
    const int z   = nid >> 7;                      // branch
    const int nb  = (nid >> 6) & 1;                // N column tile
    const int mb  = nid & 63;                      // M tile

    const float*  X    = z ? X2    : X1;
    const bf16_t* WT   = z ? WT2   : WT1;
    const float*  bias = z ? bias2 : bias1;
    const bf16_t* WC   = z ? WC2   : WC1;
    float*        F    = z ? F2    : F1;

    const int m0 = mb * 256;
    const int n0 = nb * 256;

    // A slots at 0 / 32K (h0 = rows 0-127 at +0, h1 at +16K),
    // B slots at 64K / 96K. Epilogue Hs[256][264] aliases everything.
    __shared__ __align__(128) char smem[135168];

    const int tid  = threadIdx.x;
    const int lane = tid & 63;
    const int wave = tid >> 6;
    const int wm   = wave >> 2;      // 0..1
    const int wn   = wave & 3;       // 0..3
    const int l15  = lane & 15;
    const int g4   = lane >> 4;

    // ---- staging constants (64-row unit): row = u*64 + (tid>>3)
    const int srow = tid >> 3;                    // 0..63
    const int sch  = (tid & 7) ^ (srow & 7);      // swizzled source k-chunk
    const float*  gX = X  + (size_t)(m0 + srow) * DIN + sch * 8;
    const bf16_t* gB = WT + (size_t)(n0 + srow) * DIN + sch * 8;
    const int ldst = tid * 16;                    // lane-linear LDS dest

    // ---- fragment-read constants (row&7 == l15&7: row bases are mult of 8)
    const int l7   = l15 & 7;
    const int lch0 = (g4 ^ l7) * 16;              // k-chunks 0-3 (u=0)
    const int lch1 = ((4 + g4) ^ l7) * 16;        // k-chunks 4-7 (u=1)
    const int abase = (wm * 64 + l15) * 128;      // A row byte base in half
    const int bbase = (wn * 64 + l15) * 128;      // B row byte base

    f32x4 acc[2][4][4] = {};                      // [row-half][mi][ni]
    float4 rA0, rA1, rA2, rA3;                    // A h0 prefetch (16 VGPR)
    float4 rB0, rB1, rB2, rB3;                    // A h1 prefetch (16 VGPR)

    // ---- prologue: B(0) gl2lds (early) ; A(0) direct cvt; rA <- A(1)h0
    #pragma unroll
    for (int u = 0; u < 4; u++)
        gl2lds16(gB + (size_t)u * 64 * DIN, smem + 65536 + u * 8192 + ldst);
    // A(0)h0
    rA0 = *(const float4*)(gX);
    rA1 = *(const float4*)(gX + 4);
    rA2 = *(const float4*)(gX + (size_t)64 * DIN);
    rA3 = *(const float4*)(gX + (size_t)64 * DIN + 4);
    *(bf16x8*)(smem + ldst)        = cvt8(rA0, rA1);
    *(bf16x8*)(smem + 8192 + ldst) = cvt8(rA2, rA3);
    // A(0)h1
    rB0 = *(const float4*)(gX + (size_t)128 * DIN);
    rB1 = *(const float4*)(gX + (size_t)128 * DIN + 4);
    rB2 = *(const float4*)(gX + (size_t)192 * DIN);
    rB3 = *(const float4*)(gX + (size_t)192 * DIN + 4);
    *(bf16x8*)(smem + 16384 + ldst)        = cvt8(rB0, rB1);
    *(bf16x8*)(smem + 16384 + 8192 + ldst) = cvt8(rB2, rB3);
    // rA <- A(1)h0 (left in flight across the barrier)
    rA0 = *(const float4*)(gX + 64);
    rA1 = *(const float4*)(gX + 64 + 4);
    rA2 = *(const float4*)(gX + (size_t)64 * DIN + 64);
    rA3 = *(const float4*)(gX + (size_t)64 * DIN + 64 + 4);
    __builtin_amdgcn_sched_barrier(0);
    asm volatile("s_waitcnt vmcnt(4) lgkmcnt(0)" ::: "memory");  // drain B(0); keep rA
    __builtin_amdgcn_s_barrier();
    __builtin_amdgcn_sched_barrier(0);

    #pragma unroll 1
    for (int kt = 0; kt < 16; ++kt) {
        const int d = kt & 1;
        const char* Ac = smem + d * 32768;
        const char* Bc = smem + 65536 + d * 32768;
        char* An = (char*)smem + (d ^ 1) * 32768;
        char* Bn = (char*)smem + 65536 + (d ^ 1) * 32768;
        const int kc1 = (kt < 15 ? kt + 1 : 15) * 64;   // A-h1 / B col (clamped)
        const int kc2 = (kt < 14 ? kt + 2 : 15) * 64;   // next A-h0 col

        // ---- tile top: issue rB <- A(kt+1)h1 + B(kt+1) (full-tile cover)
        rB0 = *(const float4*)(gX + (size_t)128 * DIN + kc1);
        rB1 = *(const float4*)(gX + (size_t)128 * DIN + kc1 + 4);
        rB2 = *(const float4*)(gX + (size_t)192 * DIN + kc1);
        rB3 = *(const float4*)(gX + (size_t)192 * DIN + kc1 + 4);
        __builtin_amdgcn_sched_barrier(0);
        gl2lds16(gB + (size_t)0 * 64 * DIN + kc1, Bn + 0 * 8192 + ldst);
        gl2lds16(gB + (size_t)1 * 64 * DIN + kc1, Bn + 1 * 8192 + ldst);
        gl2lds16(gB + (size_t)2 * 64 * DIN + kc1, Bn + 2 * 8192 + ldst);
        gl2lds16(gB + (size_t)3 * 64 * DIN + kc1, Bn + 3 * 8192 + ldst);
        __builtin_amdgcn_sched_barrier(0);

        // ---- compute h0: frag reads (a-h0 + all b) + 32 MFMA
        bf16x8 a[4][2], b[4][2];
        #pragma unroll
        for (int mi = 0; mi < 4; mi++) {
            a[mi][0] = *(const bf16x8*)(Ac + abase + mi * 2048 + lch0);
            a[mi][1] = *(const bf16x8*)(Ac + abase + mi * 2048 + lch1);
        }
        #pragma unroll
        for (int ni = 0; ni < 4; ni++) {
            b[ni][0] = *(const bf16x8*)(Bc + bbase + ni * 2048 + lch0);
            b[ni][1] = *(const bf16x8*)(Bc + bbase + ni * 2048 + lch1);
        }
        __builtin_amdgcn_s_setprio(1);
        #pragma unroll
        for (int mi = 0; mi < 4; mi++)
            #pragma unroll
            for (int ni = 0; ni < 4; ni++) {
                acc[0][mi][ni] = MFMA16(a[mi][0], b[ni][0], acc[0][mi][ni], 0, 0, 0);
                acc[0][mi][ni] = MFMA16(a[mi][1], b[ni][1], acc[0][mi][ni], 0, 0, 0);
            }
        __builtin_amdgcn_s_setprio(0);
        __builtin_amdgcn_sched_barrier(0);

        // ---- cvt-write A(kt+1)h0 (rA loaded mid-tile kt-1; auto vmcnt)
        *(bf16x8*)(An + ldst)        = cvt8(rA0, rA1);
        *(bf16x8*)(An + 8192 + ldst) = cvt8(rA2, rA3);
        __builtin_amdgcn_sched_barrier(0);
        // ---- mid-tile: issue rA <- A(kt+2)h0
        rA0 = *(const float4*)(gX + kc2);
        rA1 = *(const float4*)(gX + kc2 + 4);
        rA2 = *(const float4*)(gX + (size_t)64 * DIN + kc2);
        rA3 = *(const float4*)(gX + (size_t)64 * DIN + kc2 + 4);
        __builtin_amdgcn_sched_barrier(0);

        // ---- compute h1: frag reads (a-h1; b live in regs) + 32 MFMA
        bf16x8 a2[4][2];
        #pragma unroll
        for (int mi = 0; mi < 4; mi++) {
            a2[mi][0] = *(const bf16x8*)(Ac + 16384 + abase + mi * 2048 + lch0);
            a2[mi][1] = *(const bf16x8*)(Ac + 16384 + abase + mi * 2048 + lch1);
        }
        __builtin_amdgcn_s_setprio(1);
        #pragma unroll
        for (int mi = 0; mi < 4; mi++)
            #pragma unroll
            for (int ni = 0; ni < 4; ni++) {
                acc[1][mi][ni] = MFMA16(a2[mi][0], b[ni][0], acc[1][mi][ni], 0, 0, 0);
                acc[1][mi][ni] = MFMA16(a2[mi][1], b[ni][1], acc[1][mi][ni], 0, 0, 0);
            }
        __builtin_amdgcn_s_setprio(0);
        __builtin_amdgcn_sched_barrier(0);

        // ---- cvt-write A(kt+1)h1 (rB loaded at tile top; auto vmcnt)
        *(bf16x8*)(An + 16384 + ldst)        = cvt8(rB0, rB1);
        *(bf16x8*)(An + 16384 + 8192 + ldst) = cvt8(rB2, rB3);
        __builtin_amdgcn_sched_barrier(0);

        // ---- single end-of-tile sync: drain B(kt+1) + all DS; keep rA
        asm volatile("s_waitcnt vmcnt(4) lgkmcnt(0)" ::: "memory");
        __builtin_amdgcn_s_barrier();
        __builtin_amdgcn_sched_barrier(0);
    }

    // drain stray tail loads before aliasing smem
    asm volatile("s_waitcnt vmcnt(0) lgkmcnt(0)" ::: "memory");
    __builtin_amdgcn_s_barrier();

    // ---- epilogue phase 1: Hs[256][264] = relu(H + bias)  (aliases smem)
    bf16_t* Hs = (bf16_t*)smem;
    float bv[4];
    #pragma unroll
    for (int ni = 0; ni < 4; ni++)
        bv[ni] = bias[n0 + wn * 64 + ni * 16 + l15];
    #pragma unroll
    for (int ph = 0; ph < 2; ph++) {
        #pragma unroll
        for (int mi = 0; mi < 4; mi++) {
            const int lr = ph * 128 + wm * 64 + mi * 16 + g4 * 4;
            #pragma unroll
            for (int ni = 0; ni < 4; ni++) {
                const int colL = wn * 64 + ni * 16 + l15;
                #pragma unroll
                for (int r = 0; r < 4; r++) {
                    float v = fmaxf(acc[ph][mi][ni][r] + bv[ni], 0.0f);
                    Hs[(lr + r) * 264 + colL] = (bf16_t)v;
                }
            }
        }
    }
    __syncthreads();

    // ---- epilogue phase 2: each wave F[32 rows][64] += Hs-slice @ wct
    f32x4 acc2[2][4] = {};
    #pragma unroll
    for (int kk = 0; kk < 256; kk += 32) {
        bf16x8 af2[2];
        #pragma unroll
        for (int m2 = 0; m2 < 2; m2++)
            af2[m2] = *(const bf16x8*)(Hs + (wave * 32 + m2 * 16 + l15) * 264 + kk + g4 * 8);
        #pragma unroll
        for (int ni = 0; ni < 4; ni++) {
            bf16x8 bw = *(const bf16x8*)(&WC[(size_t)(ni * 16 + l15) * HID + n0 + kk + g4 * 8]);
            #pragma unroll
            for (int m2 = 0; m2 < 2; m2++)
                acc2[m2][ni] = MFMA16(af2[m2], bw, acc2[m2][ni], 0, 0, 0);
        }
    }
    #pragma unroll
    for (int m2 = 0; m2 < 2; m2++) {
        const int rbase = m0 + wave * 32 + m2 * 16 + g4 * 4;
        #pragma unroll
        for (int ni = 0; ni < 4; ni++) {
            const int col = ni * 16 + l15;
            #pragma unroll
            for (int r = 0; r < 4; r++)
                unsafeAtomicAdd(&F[(size_t)(rbase + r) * COMP + col], acc2[m2][ni][r]);
        }
    }
}

// ---------------------------------------------------------------------------
// bilinear (fp32, G-broadcast form — unchanged):
//   out[b][j] = f2[b,:] . G_j . f1[b,:]^T + c[j]
// ---------------------------------------------------------------------------
__global__ __launch_bounds__(256) void k_bilinear(
    const float* __restrict__ f1, const float* __restrict__ f2,
    const float* __restrict__ G, const float* __restrict__ c,
    float* __restrict__ out)
{
    __shared__ float Gs[2][4096];
    __shared__ float f1t[64][66];
    __shared__ float f2t[64][66];
    __shared__ float part[4][64];

    const int tid = threadIdx.x;
    const int s0  = blockIdx.x * 64;

    for (int i = tid; i < 2048; i += 256)
        reinterpret_cast<float4*>(&Gs[0][0])[i] =
            reinterpret_cast<const float4*>(G)[i];

    #pragma unroll
    for (int rr = 0; rr < 4; rr++) {
        const int row = (tid >> 4) + rr * 16;     // sample within tile
        const int c4  = (tid & 15) * 4;
        float4 v1 = *reinterpret_cast<const float4*>(&f1[(size_t)(s0 + row) * 64 + c4]);
        float4 v2 = *reinterpret_cast<const float4*>(&f2[(size_t)(s0 + row) * 64 + c4]);
        f1t[c4 + 0][row] = v1.x; f1t[c4 + 1][row] = v1.y;
        f1t[c4 + 2][row] = v1.z; f1t[c4 + 3][row] = v1.w;
        f2t[c4 + 0][row] = v2.x; f2t[c4 + 1][row] = v2.y;
        f2t[c4 + 2][row] = v2.z; f2t[c4 + 3][row] = v2.w;
    }
    __syncthreads();

    const int lane = tid & 63;        // sample
    const int wv   = tid >> 6;        // 0..3
    const int j    = wv & 1;
    const int qh   = (wv >> 1) * 32;

    float tq[32];
    #pragma unroll
    for (int q = 0; q < 32; q++) tq[q] = 0.f;

    #pragma unroll 4
    for (int p = 0; p < 64; p++) {
        const float f2p = f2t[p][lane];
        const float* Gp = &Gs[j][p * 64 + qh];
        #pragma unroll
        for (int q4 = 0; q4 < 8; q4++) {
            float4 g = *reinterpret_cast<const float4*>(Gp + q4 * 4);
            tq[q4 * 4 + 0] = fmaf(f2p, g.x, tq[q4 * 4 + 0]);
            tq[q4 * 4 + 1] = fmaf(f2p, g.y, tq[q4 * 4 + 1]);
            tq[q4 * 4 + 2] = fmaf(f2p, g.z, tq[q4 * 4 + 2]);
            tq[q4 * 4 + 3] = fmaf(f2p, g.w, tq[q4 * 4 + 3]);
        }
    }

    float o = 0.f;
    #pragma unroll
    for (int q = 0; q < 32; q++)
        o = fmaf(f1t[qh + q][lane], tq[q], o);

    part[wv][lane] = o;
    __syncthreads();

    if (wv < 2) {
        float r = part[wv][lane] + part[wv + 2][lane] + c[wv];
        out[(size_t)(s0 + lane) * 2 + wv] = r;
    }
}

// ---------------------------------------------------------------------------
extern "C" void kernel_launch(void* const* d_in, const int* in_sizes, int n_in,
                              void* d_out, int out_size, void* d_ws, size_t ws_size,
                              hipStream_t stream)
{
    const float* x1  = (const float*)d_in[0];
    const float* x2  = (const float*)d_in[1];
    const float* Wb1 = (const float*)d_in[2];
    const float* bb1 = (const float*)d_in[3];
    const float* Wb2 = (const float*)d_in[4];
    const float* bb2 = (const float*)d_in[5];
    const float* Wc1 = (const float*)d_in[6];
    const float* bc1 = (const float*)d_in[7];
    const float* Wc2 = (const float*)d_in[8];
    const float* bc2 = (const float*)d_in[9];
    const float* Wf1 = (const float*)d_in[10];
    const float* bf1v = (const float*)d_in[11];
    const float* Wf2 = (const float*)d_in[12];
    const float* bf2v = (const float*)d_in[13];
    float* out = (float*)d_out;

    // workspace carve-up (~10.8 MB)
    char* ws = (char*)d_ws;
    bf16_t* wbt1 = (bf16_t*)ws; ws += (size_t)HID * DIN * 2;
    bf16_t* wbt2 = (bf16_t*)ws; ws += (size_t)HID * DIN * 2;
    bf16_t* wct1 = (bf16_t*)ws; ws += (size_t)COMP * HID * 2;
    bf16_t* wct2 = (bf16_t*)ws; ws += (size_t)COMP * HID * 2;
    float*  f1   = (float*)ws;  ws += (size_t)B_SZ * COMP * 4;
    float*  f2   = (float*)ws;  ws += (size_t)B_SZ * COMP * 4;
    float*  G    = (float*)ws;  ws += (size_t)2 * 4096 * 4;
    float*  c    = (float*)ws;  ws += 256;

    k_prep<<<3152, 256, 0, stream>>>(Wb1, Wb2, wbt1, wbt2,
                                     Wc1, Wc2, wct1, wct2,
                                     Wf1, bf1v, Wf2, bf2v,
                                     bc1, bc2, f1, f2, G, c);
    k_gemm1f<<<256, 512, 0, stream>>>(x1, x2, wbt1, wbt2, bb1, bb2,
                                      wct1, wct2, f1, f2);
    k_bilinear<<<256, 256, 0, stream>>>(f1, f2, G, c, out);
}